// Round 11
// baseline (221.018 us; speedup 1.0000x reference)
//
#include <hip/hip_runtime.h>

#define SEQ     2048
#define HDIM    1024
#define TOKENS  4096   // B*SEQ
#define NHEADS  16
#define HS      64
#define LP      72     // padded LDS row stride for Q/P region only

typedef __bf16 v8bf __attribute__((ext_vector_type(8)));
typedef float  v4f  __attribute__((ext_vector_type(4)));

#define MFMA16(a, b, c) __builtin_amdgcn_mfma_f32_16x16x32_bf16((a), (b), (c), 0, 0, 0)

// scores arrive in log2 units: 1/sqrt(64) * log2(e) folded into Q pre-scale
#define QSCALE (0.125f * 1.44269504088896f)

__device__ __forceinline__ unsigned short f2bf(float f) {
  unsigned int u = __float_as_uint(f);
  u += 0x7FFFu + ((u >> 16) & 1u);   // RNE
  return (unsigned short)(u >> 16);
}

__device__ __forceinline__ void async16(const void* g, void* l) {
  __builtin_amdgcn_global_load_lds(
      (const __attribute__((address_space(1))) void*)g,
      (__attribute__((address_space(3))) void*)l, 16, 0, 0);
}

// ---------------- fused prep: x casts + both weight transposes ----------------
__global__ __launch_bounds__(256) void prep_all_kernel(
    const float* __restrict__ x, const float* __restrict__ pos,
    const float* __restrict__ Wqkv, const float* __restrict__ Wout,
    unsigned short* __restrict__ X, unsigned short* __restrict__ XP,
    unsigned short* __restrict__ WQT, unsigned short* __restrict__ WOT) {
  __shared__ float tile[32][33];
  const int id = blockIdx.x;
  if (id < 4096) {
    const int i = (id * 256 + threadIdx.x) * 4;
    float4 xv = *(const float4*)(x + i);
    float4 pv = *(const float4*)(pos + (i & (SEQ * HDIM - 1)));
    ushort4 a, b;
    a.x = f2bf(xv.x); a.y = f2bf(xv.y); a.z = f2bf(xv.z); a.w = f2bf(xv.w);
    b.x = f2bf(xv.x + pv.x); b.y = f2bf(xv.y + pv.y);
    b.z = f2bf(xv.z + pv.z); b.w = f2bf(xv.w + pv.w);
    *(ushort4*)(X + i) = a;
    *(ushort4*)(XP + i) = b;
    return;
  }
  const float* in; unsigned short* out; int R, C, bx, by;
  if (id < 7168) {
    const int t2 = id - 4096;
    in = Wqkv; out = WQT; R = HDIM; C = 3 * HDIM;
    bx = (t2 % 96) * 32; by = (t2 / 96) * 32;
  } else {
    const int t3 = id - 7168;
    in = Wout; out = WOT; R = HDIM; C = HDIM;
    bx = (t3 & 31) * 32; by = (t3 >> 5) * 32;
  }
  const int tx = threadIdx.x & 31, ty = threadIdx.x >> 5;  // (32,8)
#pragma unroll
  for (int j = 0; j < 32; j += 8)
    tile[ty + j][tx] = in[(size_t)(by + ty + j) * C + bx + tx];
  __syncthreads();
#pragma unroll
  for (int j = 0; j < 32; j += 8)
    out[(size_t)(bx + ty + j) * R + by + tx] = f2bf(tile[tx][ty + j]);
}

// ---------------- GEMM1: C(4096x3072) = Aeff(4096x1024) @ Wt(3072x1024)^T ----------------
// R0 serial 2-barrier structure + R6 chunk-XOR LDS swizzle (CONFIRMED:
// SQ_LDS_BANK_CONFLICT 3.15M -> 0, 42.3us = 609 TF, at the 2-barrier-128^2
// structure ceiling; R1/R2/R3 measured all pipeline corners as regressions).
// Physical 16B-chunk p holds semantic chunk s = p ^ ((p>>3)&7); staging
// pre-permutes the GLOBAL source (m173 pattern); ds_reads apply the same XOR.
// V blocks compute C^T via operand swap so the V^T store is 32B s-runs.
__global__ __launch_bounds__(256) void gemm_qkv_kernel(
    const unsigned short* __restrict__ XP, const unsigned short* __restrict__ X,
    const unsigned short* __restrict__ Wt,
    unsigned short* __restrict__ Qb, unsigned short* __restrict__ Kb,
    unsigned short* __restrict__ VTb) {
  __shared__ unsigned short As[2][128 * 32];
  __shared__ unsigned short Bs[2][128 * 32];
  const int m0 = blockIdx.x * 128;
  const int n0 = blockIdx.y * 128;
  const bool isV = (n0 >= 2 * HDIM);
  const unsigned short* A = isV ? X : XP;
  const int t = threadIdx.x;
  const int lane = t & 63, w = t >> 6;
  const int wm = (w >> 1) * 64, wn = (w & 1) * 64;
  const int quad = lane >> 4, l15 = lane & 15;

  v4f acc[4][4] = {};

  const int s0c = t ^ ((t >> 3) & 7);
  const int rowA = s0c >> 2;          // 0..63
  const int colA = (s0c & 3) * 8;
  const unsigned short* gA = A + (size_t)(m0 + rowA) * HDIM + colA;
  const unsigned short* gB = Wt + (size_t)(n0 + rowA) * HDIM + colA;

  const int baseA = 4 * (wm + l15) + quad;
  const int pA0 = (baseA ^ ((baseA >> 3) & 7)) * 8;   // element offset, +i*512
  const int baseB = 4 * (wn + l15) + quad;
  const int pB0 = (baseB ^ ((baseB >> 3) & 7)) * 8;

  for (int k0 = 0; k0 < HDIM; k0 += 64) {
    __syncthreads();
#pragma unroll
    for (int kh = 0; kh < 2; kh++) {
      async16(gA + k0 + kh * 32, &As[kh][t * 8]);
      async16(gA + 64 * HDIM + k0 + kh * 32, &As[kh][2048 + t * 8]);
      async16(gB + k0 + kh * 32, &Bs[kh][t * 8]);
      async16(gB + 64 * HDIM + k0 + kh * 32, &Bs[kh][2048 + t * 8]);
    }
    __syncthreads();
#pragma unroll
    for (int kh = 0; kh < 2; kh++) {
      v8bf a[4], b[4];
#pragma unroll
      for (int i = 0; i < 4; i++)
        a[i] = *(const v8bf*)&As[kh][pA0 + i * 512];
#pragma unroll
      for (int i = 0; i < 4; i++)
        b[i] = *(const v8bf*)&Bs[kh][pB0 + i * 512];
      if (isV) {
#pragma unroll
        for (int i = 0; i < 4; i++)
#pragma unroll
          for (int j = 0; j < 4; j++)
            acc[i][j] = MFMA16(b[j], a[i], acc[i][j]);   // C^T
      } else {
#pragma unroll
        for (int i = 0; i < 4; i++)
#pragma unroll
          for (int j = 0; j < 4; j++)
            acc[i][j] = MFMA16(a[i], b[j], acc[i][j]);
      }
    }
  }

  const int b_ = m0 >> 11;
  const int s0 = m0 & (SEQ - 1);

  if (isV) {
    // acc[i][j] = C^T: D[row=quad*4+r -> Wt col (d)][col=l15 -> token (s)]
#pragma unroll
    for (int i = 0; i < 4; i++) {
#pragma unroll
      for (int j = 0; j < 4; j++) {
        const int s_ = s0 + wm + i * 16 + l15;
#pragma unroll
        for (int r = 0; r < 4; r++) {
          const int c2 = (n0 - 2 * HDIM) + wn + j * 16 + quad * 4 + r;
          const int h = c2 >> 6, d = c2 & 63;
          VTb[((size_t)(((b_ << 4) | h) * HS + d)) * SEQ + s_] = f2bf(acc[i][j][r]);
        }
      }
    }
  } else {
    // Q/K[(b,h,s), d]: scatter, 16 consecutive lanes form 32B d-runs
    const float scale = (n0 < HDIM) ? QSCALE : 1.0f;
    unsigned short* dst = (n0 < HDIM) ? Qb : Kb;
#pragma unroll
    for (int i = 0; i < 4; i++) {
#pragma unroll
      for (int j = 0; j < 4; j++) {
#pragma unroll
        for (int r = 0; r < 4; r++) {
          const int s_ = s0 + wm + i * 16 + quad * 4 + r;
          const int c2 = (n0 & (HDIM - 1)) + wn + j * 16 + l15;
          const int h = c2 >> 6, d = c2 & 63;
          dst[((size_t)(((b_ << 4) | h) * SEQ + s_)) * HS + d] =
              f2bf(acc[i][j][r] * scale);
        }
      }
    }
  }
}

// ---------------- flash attention, single-tile blocks (R8) + R11 de-staging ----
// ONE 64-row q-tile per block, grid 32bh x 32q = 1024 blocks (4/CU); heavy-
// first dispatch q = 31 - blockIdx.y; T5 setprio around MFMA clusters (R9).
// R11a: V is NOT staged in LDS — guide Common-mistake #7 (m169: +26% attn at
// L2-fit). Each XCD sees 4 bh x 512KB = 2MB K/V -> L2-resident; V fragments
// load DIRECTLY global->reg (lane reads V^T[ni*16+l15][kc+ki*32+quad*8..+7],
// one aligned 16B load = identical bytes to the old LDS path), issued before
// the barrier so L2 latency hides under QK^T+softmax.
// R11b: Ks double-buffered (2x8KB; LDS total 25,600B unchanged) -> ONE
// __syncthreads per chunk. WAR-safe: chunk c writes buf[c&1]; prior readers
// (chunk c-2) are separated by the collective chunk c-1 barrier. Ps regions
// are per-wave private (no barrier needed); per-wave LDS ops are in-order so
// the pre-loop bq reads complete before that wave's Ps writes.
__global__ __launch_bounds__(256, 2) void attn_pair_kernel(
    const unsigned short* __restrict__ Qp, const unsigned short* __restrict__ Kp,
    const unsigned short* __restrict__ Vp, unsigned short* __restrict__ ATTN) {
  __shared__ unsigned short SM[12800];       // 25,600 B
  unsigned short* Ks = SM;                   // [2][64][64] dbuf, XOR-swizzled
  unsigned short* QPs = SM + 8192;           // 64*LP union: Qs (init) / Ps (loop)

  const int bh = blockIdx.x;                 // 0..31
  const int qt = 31 - blockIdx.y;            // heavy-first
  const int b_ = bh >> 4, h = bh & 15;
  const int q0 = qt * 64;
  const int t = threadIdx.x;
  const int lane = t & 63, w = t >> 6;
  const int quad = lane >> 4, l15 = lane & 15;

  const unsigned short* Qg = Qp + (size_t)bh * SEQ * HS;
  const unsigned short* Kg = Kp + (size_t)bh * SEQ * HS;
  const unsigned short* Vg = Vp + (size_t)bh * HS * SEQ;

  const int sr = t >> 3, scol = (t & 7) * 8;
  const int pst = (t ^ ((t >> 3) & 7)) * 8;
  const int xq0 = (quad ^ (l15 & 7)) * 8;
  const int xq1 = ((quad + 4) ^ (l15 & 7)) * 8;

  // Q staging: 64 rows
  *(uint4*)&QPs[sr * LP + scol] = *(const uint4*)(Qg + (size_t)(q0 + sr) * HS + scol);
  *(uint4*)&QPs[(sr + 32) * LP + scol] =
      *(const uint4*)(Qg + (size_t)(q0 + sr + 32) * HS + scol);
  __syncthreads();

  v8bf bq[2];
#pragma unroll
  for (int kh = 0; kh < 2; kh++)
    bq[kh] = *(const v8bf*)&QPs[(w * 16 + l15) * LP + kh * 32 + quad * 8];

  unsigned short* Ps_w = QPs + w * 16 * LP;  // 16 rows/wave

  v8bf ones;
#pragma unroll
  for (int j = 0; j < 8; j++) ones[j] = (__bf16)1.0f;

  v4f o[4] = {};
  v4f lacc = {};

  // register prefetch of chunk 0 (K only; V reads are direct per-fragment)
  uint4 kr0, kr1;
  kr0 = *(const uint4*)(Kg + (size_t)sr * HS + scol);
  kr1 = *(const uint4*)(Kg + (size_t)(sr + 32) * HS + scol);

  const int qrow = q0 + w * 16 + l15;  // lane's q-row in S^T
  const unsigned short* Vrow = Vg + (size_t)l15 * SEQ;  // + ni*16*SEQ

  for (int cI = 0; cI <= qt; cI++) {
    const int kc = cI * 64;
    unsigned short* Kbuf = Ks + (cI & 1) * 4096;
    // stage K chunk (WAR vs chunk cI-2 readers covered by chunk cI-1 barrier)
    *(uint4*)&Kbuf[pst] = kr0;
    *(uint4*)&Kbuf[pst + 2048] = kr1;
    if (cI < qt) {  // prefetch next K chunk
      const int kn = kc + 64;
      kr0 = *(const uint4*)(Kg + (size_t)(kn + sr) * HS + scol);
      kr1 = *(const uint4*)(Kg + (size_t)(kn + sr + 32) * HS + scol);
    }
    // V fragments for THIS chunk: direct global loads, consumed in PV
    v8bf vf[2][4];
#pragma unroll
    for (int ki = 0; ki < 2; ki++)
#pragma unroll
      for (int ni = 0; ni < 4; ni++)
        vf[ki][ni] = *(const v8bf*)(Vrow + (size_t)(ni * 16) * SEQ +
                                    kc + ki * 32 + quad * 8);
    __syncthreads();  // single barrier per chunk

    // K fragments (A-operand)
    v8bf kf0[4], kf1[4];
#pragma unroll
    for (int ni = 0; ni < 4; ni++) {
      kf0[ni] = *(const v8bf*)&Kbuf[(ni * 16 + l15) * 64 + xq0];
      kf1[ni] = *(const v8bf*)&Kbuf[(ni * 16 + l15) * 64 + xq1];
    }

    // ---- S^T = K Q^T, D[key=quad*4+r][qrow=l15] ----
    {
      v4f sc[4] = {};
      __builtin_amdgcn_s_setprio(1);
#pragma unroll
      for (int ni = 0; ni < 4; ni++) {
        sc[ni] = MFMA16(kf0[ni], bq[0], sc[ni]);
        sc[ni] = MFMA16(kf1[ni], bq[1], sc[ni]);
      }
      __builtin_amdgcn_s_setprio(0);
      if (cI == qt) {
#pragma unroll
        for (int ni = 0; ni < 4; ni++) {
          const int key = kc + ni * 16 + quad * 4;
#pragma unroll
          for (int r = 0; r < 4; r++)
            if (key + r > qrow) sc[ni][r] = -1e30f;
        }
      }
#pragma unroll
      for (int ni = 0; ni < 4; ni++) {
        const float p0 = exp2f(sc[ni][0]), p1 = exp2f(sc[ni][1]);
        const float p2 = exp2f(sc[ni][2]), p3 = exp2f(sc[ni][3]);
        uint2 pk;
        pk.x = __builtin_amdgcn_perm(__float_as_uint(p1), __float_as_uint(p0), 0x07060302u);
        pk.y = __builtin_amdgcn_perm(__float_as_uint(p3), __float_as_uint(p2), 0x07060302u);
        *(uint2*)&Ps_w[l15 * LP + ni * 16 + quad * 4] = pk;
      }
    }

    // ---- O += P @ V, l += P @ 1 (V from registers) ----
    __builtin_amdgcn_s_setprio(1);
#pragma unroll
    for (int ki = 0; ki < 2; ki++) {
      v8bf pa = *(const v8bf*)&Ps_w[l15 * LP + ki * 32 + quad * 8];
      lacc = MFMA16(pa, ones, lacc);
#pragma unroll
      for (int ni = 0; ni < 4; ni++)
        o[ni] = MFMA16(pa, vf[ki][ni], o[ni]);
    }
    __builtin_amdgcn_s_setprio(0);
  }

  // epilogue: normalize and store (C-layout rows = quad*4+r)
  const int row_base = q0 + w * 16 + quad * 4;
  float invl[4];
#pragma unroll
  for (int r = 0; r < 4; r++) invl[r] = 1.0f / lacc[r];
#pragma unroll
  for (int ni = 0; ni < 4; ni++)
#pragma unroll
    for (int r = 0; r < 4; r++) {
      const int tr = b_ * SEQ + row_base + r;
      ATTN[(size_t)tr * HDIM + h * HS + ni * 16 + l15] = f2bf(o[ni][r] * invl[r]);
    }
}

// ---------------- GEMM2: out(4096x1024) = ATTN @ WOT^T, fp32 out ----------------
// 64x64-tile clone of gemm_qkv's serial BK=64 2-barrier structure (R10;
// neutral vs old shape at total level — kept: simpler, 4 blocks/CU).
// Chunk-XOR swizzle carried over verbatim (R6-verified).
__global__ __launch_bounds__(256) void gemm_out_kernel(
    const unsigned short* __restrict__ Ab, const unsigned short* __restrict__ Wt,
    float* __restrict__ out) {
  __shared__ unsigned short As[2][64 * 32];
  __shared__ unsigned short Bs[2][64 * 32];
  const int m0 = blockIdx.x * 64;
  const int n0 = blockIdx.y * 64;
  const int t = threadIdx.x;
  const int lane = t & 63, w = t >> 6;
  const int wm = (w >> 1) * 32, wn = (w & 1) * 32;   // wave tile 32x32
  const int quad = lane >> 4, l15 = lane & 15;

  v4f acc[2][2] = {};

  const int s0c = t ^ ((t >> 3) & 7);
  const int rowA = s0c >> 2;          // 0..63
  const int colA = (s0c & 3) * 8;
  const unsigned short* gA = Ab + (size_t)(m0 + rowA) * HDIM + colA;
  const unsigned short* gB = Wt + (size_t)(n0 + rowA) * HDIM + colA;

  const int baseA = 4 * (wm + l15) + quad;
  const int pA0 = (baseA ^ ((baseA >> 3) & 7)) * 8;
  const int baseB = 4 * (wn + l15) + quad;
  const int pB0 = (baseB ^ ((baseB >> 3) & 7)) * 8;

  for (int k0 = 0; k0 < HDIM; k0 += 64) {
    __syncthreads();
#pragma unroll
    for (int kh = 0; kh < 2; kh++) {
      async16(gA + k0 + kh * 32, &As[kh][t * 8]);
      async16(gB + k0 + kh * 32, &Bs[kh][t * 8]);
    }
    __syncthreads();
#pragma unroll
    for (int kh = 0; kh < 2; kh++) {
      v8bf a[2], b[2];
#pragma unroll
      for (int i = 0; i < 2; i++)
        a[i] = *(const v8bf*)&As[kh][pA0 + i * 512];
#pragma unroll
      for (int j = 0; j < 2; j++)
        b[j] = *(const v8bf*)&Bs[kh][pB0 + j * 512];
#pragma unroll
      for (int i = 0; i < 2; i++)
#pragma unroll
        for (int j = 0; j < 2; j++)
          acc[i][j] = MFMA16(a[i], b[j], acc[i][j]);
    }
  }

#pragma unroll
  for (int i = 0; i < 2; i++) {
#pragma unroll
    for (int j = 0; j < 2; j++) {
#pragma unroll
      for (int r = 0; r < 4; r++) {
        const int tr = m0 + wm + i * 16 + quad * 4 + r;
        const int c = n0 + wn + j * 16 + l15;
        out[(size_t)tr * HDIM + c] = acc[i][j][r];
      }
    }
  }
}

extern "C" void kernel_launch(void* const* d_in, const int* in_sizes, int n_in,
                              void* d_out, int out_size, void* d_ws, size_t ws_size,
                              hipStream_t stream) {
  (void)in_sizes; (void)n_in; (void)out_size; (void)ws_size;
  const float* x    = (const float*)d_in[0];
  const float* pos  = (const float*)d_in[1];
  const float* Wqkv = (const float*)d_in[2];
  const float* Wout = (const float*)d_in[3];
  float* out = (float*)d_out;

  char* ws = (char*)d_ws;
  unsigned short* XP   = (unsigned short*)(ws);
  unsigned short* X    = (unsigned short*)(ws + ((size_t)8  << 20));
  unsigned short* WQT  = (unsigned short*)(ws + ((size_t)16 << 20));
  unsigned short* WOT  = (unsigned short*)(ws + ((size_t)22 << 20));
  unsigned short* Qb   = (unsigned short*)(ws + ((size_t)24 << 20));
  unsigned short* Kb   = (unsigned short*)(ws + ((size_t)32 << 20));
  unsigned short* VTb  = (unsigned short*)(ws + ((size_t)40 << 20));
  unsigned short* ATTN = (unsigned short*)(ws + ((size_t)48 << 20));

  prep_all_kernel<<<8192, 256, 0, stream>>>(x, pos, Wqkv, Wout, X, XP, WQT, WOT);

  dim3 g1(TOKENS / 128, 3 * HDIM / 128);
  gemm_qkv_kernel<<<g1, 256, 0, stream>>>(XP, X, WQT, Qb, Kb, VTb);

  dim3 g2(2 * NHEADS, 32);
  attn_pair_kernel<<<g2, 256, 0, stream>>>(Qb, Kb, VTb, ATTN);

  dim3 g3(TOKENS / 64, HDIM / 64);
  gemm_out_kernel<<<g3, 256, 0, stream>>>(ATTN, WOT, out);
}

// Round 12
// 178.775 us; speedup vs baseline: 1.2363x; 1.2363x over previous
//
#include <hip/hip_runtime.h>

#define SEQ     2048
#define HDIM    1024
#define TOKENS  4096   // B*SEQ
#define NHEADS  16
#define HS      64
#define LP      72     // padded LDS row stride for Q/P region only

typedef __bf16 v8bf __attribute__((ext_vector_type(8)));
typedef float  v4f  __attribute__((ext_vector_type(4)));

#define MFMA16(a, b, c) __builtin_amdgcn_mfma_f32_16x16x32_bf16((a), (b), (c), 0, 0, 0)

// scores arrive in log2 units: 1/sqrt(64) * log2(e) folded into Q pre-scale
#define QSCALE (0.125f * 1.44269504088896f)

__device__ __forceinline__ unsigned short f2bf(float f) {
  unsigned int u = __float_as_uint(f);
  u += 0x7FFFu + ((u >> 16) & 1u);   // RNE
  return (unsigned short)(u >> 16);
}

__device__ __forceinline__ void async16(const void* g, void* l) {
  __builtin_amdgcn_global_load_lds(
      (const __attribute__((address_space(1))) void*)g,
      (__attribute__((address_space(3))) void*)l, 16, 0, 0);
}

// ---------------- fused prep: x casts + both weight transposes ----------------
__global__ __launch_bounds__(256) void prep_all_kernel(
    const float* __restrict__ x, const float* __restrict__ pos,
    const float* __restrict__ Wqkv, const float* __restrict__ Wout,
    unsigned short* __restrict__ X, unsigned short* __restrict__ XP,
    unsigned short* __restrict__ WQT, unsigned short* __restrict__ WOT) {
  __shared__ float tile[32][33];
  const int id = blockIdx.x;
  if (id < 4096) {
    const int i = (id * 256 + threadIdx.x) * 4;
    float4 xv = *(const float4*)(x + i);
    float4 pv = *(const float4*)(pos + (i & (SEQ * HDIM - 1)));
    ushort4 a, b;
    a.x = f2bf(xv.x); a.y = f2bf(xv.y); a.z = f2bf(xv.z); a.w = f2bf(xv.w);
    b.x = f2bf(xv.x + pv.x); b.y = f2bf(xv.y + pv.y);
    b.z = f2bf(xv.z + pv.z); b.w = f2bf(xv.w + pv.w);
    *(ushort4*)(X + i) = a;
    *(ushort4*)(XP + i) = b;
    return;
  }
  const float* in; unsigned short* out; int R, C, bx, by;
  if (id < 7168) {
    const int t2 = id - 4096;
    in = Wqkv; out = WQT; R = HDIM; C = 3 * HDIM;
    bx = (t2 % 96) * 32; by = (t2 / 96) * 32;
  } else {
    const int t3 = id - 7168;
    in = Wout; out = WOT; R = HDIM; C = HDIM;
    bx = (t3 & 31) * 32; by = (t3 >> 5) * 32;
  }
  const int tx = threadIdx.x & 31, ty = threadIdx.x >> 5;  // (32,8)
#pragma unroll
  for (int j = 0; j < 32; j += 8)
    tile[ty + j][tx] = in[(size_t)(by + ty + j) * C + bx + tx];
  __syncthreads();
#pragma unroll
  for (int j = 0; j < 32; j += 8)
    out[(size_t)(bx + ty + j) * R + by + tx] = f2bf(tile[tx][ty + j]);
}

// ---------------- GEMM1: C(4096x3072) = Aeff(4096x1024) @ Wt(3072x1024)^T ----------------
// R0 serial 2-barrier structure + R6 chunk-XOR LDS swizzle (CONFIRMED:
// SQ_LDS_BANK_CONFLICT 3.15M -> 0, 42.3us = 609 TF, at the 2-barrier-128^2
// structure ceiling; R1/R2/R3 measured all pipeline corners as regressions).
// Physical 16B-chunk p holds semantic chunk s = p ^ ((p>>3)&7); staging
// pre-permutes the GLOBAL source (m173 pattern); ds_reads apply the same XOR.
// V blocks compute C^T via operand swap so the V^T store is 32B s-runs.
__global__ __launch_bounds__(256) void gemm_qkv_kernel(
    const unsigned short* __restrict__ XP, const unsigned short* __restrict__ X,
    const unsigned short* __restrict__ Wt,
    unsigned short* __restrict__ Qb, unsigned short* __restrict__ Kb,
    unsigned short* __restrict__ VTb) {
  __shared__ unsigned short As[2][128 * 32];
  __shared__ unsigned short Bs[2][128 * 32];
  const int m0 = blockIdx.x * 128;
  const int n0 = blockIdx.y * 128;
  const bool isV = (n0 >= 2 * HDIM);
  const unsigned short* A = isV ? X : XP;
  const int t = threadIdx.x;
  const int lane = t & 63, w = t >> 6;
  const int wm = (w >> 1) * 64, wn = (w & 1) * 64;
  const int quad = lane >> 4, l15 = lane & 15;

  v4f acc[4][4] = {};

  const int s0c = t ^ ((t >> 3) & 7);
  const int rowA = s0c >> 2;          // 0..63
  const int colA = (s0c & 3) * 8;
  const unsigned short* gA = A + (size_t)(m0 + rowA) * HDIM + colA;
  const unsigned short* gB = Wt + (size_t)(n0 + rowA) * HDIM + colA;

  const int baseA = 4 * (wm + l15) + quad;
  const int pA0 = (baseA ^ ((baseA >> 3) & 7)) * 8;   // element offset, +i*512
  const int baseB = 4 * (wn + l15) + quad;
  const int pB0 = (baseB ^ ((baseB >> 3) & 7)) * 8;

  for (int k0 = 0; k0 < HDIM; k0 += 64) {
    __syncthreads();
#pragma unroll
    for (int kh = 0; kh < 2; kh++) {
      async16(gA + k0 + kh * 32, &As[kh][t * 8]);
      async16(gA + 64 * HDIM + k0 + kh * 32, &As[kh][2048 + t * 8]);
      async16(gB + k0 + kh * 32, &Bs[kh][t * 8]);
      async16(gB + 64 * HDIM + k0 + kh * 32, &Bs[kh][2048 + t * 8]);
    }
    __syncthreads();
#pragma unroll
    for (int kh = 0; kh < 2; kh++) {
      v8bf a[4], b[4];
#pragma unroll
      for (int i = 0; i < 4; i++)
        a[i] = *(const v8bf*)&As[kh][pA0 + i * 512];
#pragma unroll
      for (int i = 0; i < 4; i++)
        b[i] = *(const v8bf*)&Bs[kh][pB0 + i * 512];
      if (isV) {
#pragma unroll
        for (int i = 0; i < 4; i++)
#pragma unroll
          for (int j = 0; j < 4; j++)
            acc[i][j] = MFMA16(b[j], a[i], acc[i][j]);   // C^T
      } else {
#pragma unroll
        for (int i = 0; i < 4; i++)
#pragma unroll
          for (int j = 0; j < 4; j++)
            acc[i][j] = MFMA16(a[i], b[j], acc[i][j]);
      }
    }
  }

  const int b_ = m0 >> 11;
  const int s0 = m0 & (SEQ - 1);

  if (isV) {
    // acc[i][j] = C^T: D[row=quad*4+r -> Wt col (d)][col=l15 -> token (s)]
#pragma unroll
    for (int i = 0; i < 4; i++) {
#pragma unroll
      for (int j = 0; j < 4; j++) {
        const int s_ = s0 + wm + i * 16 + l15;
#pragma unroll
        for (int r = 0; r < 4; r++) {
          const int c2 = (n0 - 2 * HDIM) + wn + j * 16 + quad * 4 + r;
          const int h = c2 >> 6, d = c2 & 63;
          VTb[((size_t)(((b_ << 4) | h) * HS + d)) * SEQ + s_] = f2bf(acc[i][j][r]);
        }
      }
    }
  } else {
    // Q/K[(b,h,s), d]: scatter, 16 consecutive lanes form 32B d-runs
    const float scale = (n0 < HDIM) ? QSCALE : 1.0f;
    unsigned short* dst = (n0 < HDIM) ? Qb : Kb;
#pragma unroll
    for (int i = 0; i < 4; i++) {
#pragma unroll
      for (int j = 0; j < 4; j++) {
#pragma unroll
        for (int r = 0; r < 4; r++) {
          const int s_ = s0 + wm + i * 16 + quad * 4 + r;
          const int c2 = (n0 & (HDIM - 1)) + wn + j * 16 + l15;
          const int h = c2 >> 6, d = c2 & 63;
          dst[((size_t)(((b_ << 4) | h) * SEQ + s_)) * HS + d] =
              f2bf(acc[i][j][r] * scale);
        }
      }
    }
  }
}

// ---------------- flash attention, single-tile blocks (R8/R9/R10 proven state) ----
// ONE 64-row q-tile per block, grid 32bh x 32q = 1024 blocks (4/CU); heavy-
// first dispatch q = 31 - blockIdx.y. Ks/Vs chunk-XOR swizzled (conflict
// free); Ps keeps LP=72; per-wave Ps region = own Q rows (no cross-wave WAR).
// T5 s_setprio(1/0) around both MFMA clusters (R9 win). R11's direct-V-to-reg
// REVERTED: fragment-shaped global V loads are uncoalesced (16 rows x 4KB
// apart per 16-lane group -> 16 cache lines/fragment; attn 38->84us). The
// LDS staging path reads V coalesced (contiguous 2KB runs per wave) — that,
// not byte count, is why staging wins here (G2 > Common-mistake #7).
__global__ __launch_bounds__(256, 2) void attn_pair_kernel(
    const unsigned short* __restrict__ Qp, const unsigned short* __restrict__ Kp,
    const unsigned short* __restrict__ Vp, unsigned short* __restrict__ ATTN) {
  __shared__ unsigned short SM[12800];       // 25,600 B
  unsigned short* Ks = SM;                   // [64][64] linear, XOR-swizzled
  unsigned short* Vs = SM + 4096;            // [64][64] linear (V^T: [d][key])
  unsigned short* QPs = SM + 8192;           // 64*LP union: Qs (init) / Ps (loop)

  const int bh = blockIdx.x;                 // 0..31
  const int qt = 31 - blockIdx.y;            // heavy-first
  const int b_ = bh >> 4, h = bh & 15;
  const int q0 = qt * 64;
  const int t = threadIdx.x;
  const int lane = t & 63, w = t >> 6;
  const int quad = lane >> 4, l15 = lane & 15;

  const unsigned short* Qg = Qp + (size_t)bh * SEQ * HS;
  const unsigned short* Kg = Kp + (size_t)bh * SEQ * HS;
  const unsigned short* Vg = Vp + (size_t)bh * HS * SEQ;

  const int sr = t >> 3, scol = (t & 7) * 8;
  const int pst = (t ^ ((t >> 3) & 7)) * 8;
  const int xq0 = (quad ^ (l15 & 7)) * 8;
  const int xq1 = ((quad + 4) ^ (l15 & 7)) * 8;

  // Q staging: 64 rows
  *(uint4*)&QPs[sr * LP + scol] = *(const uint4*)(Qg + (size_t)(q0 + sr) * HS + scol);
  *(uint4*)&QPs[(sr + 32) * LP + scol] =
      *(const uint4*)(Qg + (size_t)(q0 + sr + 32) * HS + scol);
  __syncthreads();

  v8bf bq[2];
#pragma unroll
  for (int kh = 0; kh < 2; kh++)
    bq[kh] = *(const v8bf*)&QPs[(w * 16 + l15) * LP + kh * 32 + quad * 8];

  unsigned short* Ps_w = QPs + w * 16 * LP;  // 16 rows/wave

  v8bf ones;
#pragma unroll
  for (int j = 0; j < 8; j++) ones[j] = (__bf16)1.0f;

  v4f o[4] = {};
  v4f lacc = {};

  // register prefetch of chunk 0
  uint4 kr0, kr1, vr0, vr1;
  kr0 = *(const uint4*)(Kg + (size_t)sr * HS + scol);
  kr1 = *(const uint4*)(Kg + (size_t)(sr + 32) * HS + scol);
  vr0 = *(const uint4*)(Vg + (size_t)sr * SEQ + scol);
  vr1 = *(const uint4*)(Vg + (size_t)(sr + 32) * SEQ + scol);

  const int qrow = q0 + w * 16 + l15;  // lane's q-row in S^T

  for (int cI = 0; cI <= qt; cI++) {
    const int kc = cI * 64;
    __syncthreads();  // previous chunk's K/V LDS reads done
    *(uint4*)&Ks[pst] = kr0;
    *(uint4*)&Ks[pst + 2048] = kr1;
    *(uint4*)&Vs[pst] = vr0;
    *(uint4*)&Vs[pst + 2048] = vr1;
    if (cI < qt) {  // prefetch next chunk while computing this one
      const int kn = kc + 64;
      kr0 = *(const uint4*)(Kg + (size_t)(kn + sr) * HS + scol);
      kr1 = *(const uint4*)(Kg + (size_t)(kn + sr + 32) * HS + scol);
      vr0 = *(const uint4*)(Vg + (size_t)sr * SEQ + kn + scol);
      vr1 = *(const uint4*)(Vg + (size_t)(sr + 32) * SEQ + kn + scol);
    }
    __syncthreads();

    // K fragments (A-operand)
    v8bf kf0[4], kf1[4];
#pragma unroll
    for (int ni = 0; ni < 4; ni++) {
      kf0[ni] = *(const v8bf*)&Ks[(ni * 16 + l15) * 64 + xq0];
      kf1[ni] = *(const v8bf*)&Ks[(ni * 16 + l15) * 64 + xq1];
    }

    // ---- S^T = K Q^T, D[key=quad*4+r][qrow=l15] ----
    {
      v4f sc[4] = {};
      __builtin_amdgcn_s_setprio(1);
#pragma unroll
      for (int ni = 0; ni < 4; ni++) {
        sc[ni] = MFMA16(kf0[ni], bq[0], sc[ni]);
        sc[ni] = MFMA16(kf1[ni], bq[1], sc[ni]);
      }
      __builtin_amdgcn_s_setprio(0);
      if (cI == qt) {
#pragma unroll
        for (int ni = 0; ni < 4; ni++) {
          const int key = kc + ni * 16 + quad * 4;
#pragma unroll
          for (int r = 0; r < 4; r++)
            if (key + r > qrow) sc[ni][r] = -1e30f;
        }
      }
#pragma unroll
      for (int ni = 0; ni < 4; ni++) {
        const float p0 = exp2f(sc[ni][0]), p1 = exp2f(sc[ni][1]);
        const float p2 = exp2f(sc[ni][2]), p3 = exp2f(sc[ni][3]);
        uint2 pk;
        pk.x = __builtin_amdgcn_perm(__float_as_uint(p1), __float_as_uint(p0), 0x07060302u);
        pk.y = __builtin_amdgcn_perm(__float_as_uint(p3), __float_as_uint(p2), 0x07060302u);
        *(uint2*)&Ps_w[l15 * LP + ni * 16 + quad * 4] = pk;
      }
    }

    // ---- O += P @ V, l += P @ 1 ----
    __builtin_amdgcn_s_setprio(1);
#pragma unroll
    for (int ki = 0; ki < 2; ki++) {
      v8bf pa = *(const v8bf*)&Ps_w[l15 * LP + ki * 32 + quad * 8];
      lacc = MFMA16(pa, ones, lacc);
      const int xqk = ki ? xq1 : xq0;
#pragma unroll
      for (int ni = 0; ni < 4; ni++) {
        v8bf vb = *(const v8bf*)&Vs[(ni * 16 + l15) * 64 + xqk];
        o[ni] = MFMA16(pa, vb, o[ni]);
      }
    }
    __builtin_amdgcn_s_setprio(0);
  }

  // epilogue: normalize and store (C-layout rows = quad*4+r)
  const int row_base = q0 + w * 16 + quad * 4;
  float invl[4];
#pragma unroll
  for (int r = 0; r < 4; r++) invl[r] = 1.0f / lacc[r];
#pragma unroll
  for (int ni = 0; ni < 4; ni++)
#pragma unroll
    for (int r = 0; r < 4; r++) {
      const int tr = b_ * SEQ + row_base + r;
      ATTN[(size_t)tr * HDIM + h * HS + ni * 16 + l15] = f2bf(o[ni][r] * invl[r]);
    }
}

// ---------------- GEMM2: out(4096x1024) = ATTN @ WOT^T, fp32 out ----------------
// 64x64-tile clone of gemm_qkv's serial BK=64 2-barrier structure (R10).
// Chunk-XOR swizzle carried over verbatim (R6-verified).
__global__ __launch_bounds__(256) void gemm_out_kernel(
    const unsigned short* __restrict__ Ab, const unsigned short* __restrict__ Wt,
    float* __restrict__ out) {
  __shared__ unsigned short As[2][64 * 32];
  __shared__ unsigned short Bs[2][64 * 32];
  const int m0 = blockIdx.x * 64;
  const int n0 = blockIdx.y * 64;
  const int t = threadIdx.x;
  const int lane = t & 63, w = t >> 6;
  const int wm = (w >> 1) * 32, wn = (w & 1) * 32;   // wave tile 32x32
  const int quad = lane >> 4, l15 = lane & 15;

  v4f acc[2][2] = {};

  const int s0c = t ^ ((t >> 3) & 7);
  const int rowA = s0c >> 2;          // 0..63
  const int colA = (s0c & 3) * 8;
  const unsigned short* gA = Ab + (size_t)(m0 + rowA) * HDIM + colA;
  const unsigned short* gB = Wt + (size_t)(n0 + rowA) * HDIM + colA;

  const int baseA = 4 * (wm + l15) + quad;
  const int pA0 = (baseA ^ ((baseA >> 3) & 7)) * 8;
  const int baseB = 4 * (wn + l15) + quad;
  const int pB0 = (baseB ^ ((baseB >> 3) & 7)) * 8;

  for (int k0 = 0; k0 < HDIM; k0 += 64) {
    __syncthreads();
#pragma unroll
    for (int kh = 0; kh < 2; kh++) {
      async16(gA + k0 + kh * 32, &As[kh][t * 8]);
      async16(gB + k0 + kh * 32, &Bs[kh][t * 8]);
    }
    __syncthreads();
#pragma unroll
    for (int kh = 0; kh < 2; kh++) {
      v8bf a[2], b[2];
#pragma unroll
      for (int i = 0; i < 2; i++)
        a[i] = *(const v8bf*)&As[kh][pA0 + i * 512];
#pragma unroll
      for (int j = 0; j < 2; j++)
        b[j] = *(const v8bf*)&Bs[kh][pB0 + j * 512];
#pragma unroll
      for (int i = 0; i < 2; i++)
#pragma unroll
        for (int j = 0; j < 2; j++)
          acc[i][j] = MFMA16(a[i], b[j], acc[i][j]);
    }
  }

#pragma unroll
  for (int i = 0; i < 2; i++) {
#pragma unroll
    for (int j = 0; j < 2; j++) {
#pragma unroll
      for (int r = 0; r < 4; r++) {
        const int tr = m0 + wm + i * 16 + quad * 4 + r;
        const int c = n0 + wn + j * 16 + l15;
        out[(size_t)tr * HDIM + c] = acc[i][j][r];
      }
    }
  }
}

extern "C" void kernel_launch(void* const* d_in, const int* in_sizes, int n_in,
                              void* d_out, int out_size, void* d_ws, size_t ws_size,
                              hipStream_t stream) {
  (void)in_sizes; (void)n_in; (void)out_size; (void)ws_size;
  const float* x    = (const float*)d_in[0];
  const float* pos  = (const float*)d_in[1];
  const float* Wqkv = (const float*)d_in[2];
  const float* Wout = (const float*)d_in[3];
  float* out = (float*)d_out;

  char* ws = (char*)d_ws;
  unsigned short* XP   = (unsigned short*)(ws);
  unsigned short* X    = (unsigned short*)(ws + ((size_t)8  << 20));
  unsigned short* WQT  = (unsigned short*)(ws + ((size_t)16 << 20));
  unsigned short* WOT  = (unsigned short*)(ws + ((size_t)22 << 20));
  unsigned short* Qb   = (unsigned short*)(ws + ((size_t)24 << 20));
  unsigned short* Kb   = (unsigned short*)(ws + ((size_t)32 << 20));
  unsigned short* VTb  = (unsigned short*)(ws + ((size_t)40 << 20));
  unsigned short* ATTN = (unsigned short*)(ws + ((size_t)48 << 20));

  prep_all_kernel<<<8192, 256, 0, stream>>>(x, pos, Wqkv, Wout, X, XP, WQT, WOT);

  dim3 g1(TOKENS / 128, 3 * HDIM / 128);
  gemm_qkv_kernel<<<g1, 256, 0, stream>>>(XP, X, WQT, Qb, Kb, VTb);

  dim3 g2(2 * NHEADS, 32);
  attn_pair_kernel<<<g2, 256, 0, stream>>>(Qb, Kb, VTb, ATTN);

  dim3 g3(TOKENS / 64, HDIM / 64);
  gemm_out_kernel<<<g3, 256, 0, stream>>>(ATTN, WOT, out);
}

// Round 13
// 178.531 us; speedup vs baseline: 1.2380x; 1.0014x over previous
//
#include <hip/hip_runtime.h>

#define SEQ     2048
#define HDIM    1024
#define TOKENS  4096   // B*SEQ
#define NHEADS  16
#define HS      64
#define LP      72     // padded LDS row stride (gemm_qkv Q/P legacy; attn now linear)

typedef __bf16 v8bf __attribute__((ext_vector_type(8)));
typedef float  v4f  __attribute__((ext_vector_type(4)));

#define MFMA16(a, b, c) __builtin_amdgcn_mfma_f32_16x16x32_bf16((a), (b), (c), 0, 0, 0)

// scores arrive in log2 units: 1/sqrt(64) * log2(e) folded into Q pre-scale
#define QSCALE (0.125f * 1.44269504088896f)

__device__ __forceinline__ unsigned short f2bf(float f) {
  unsigned int u = __float_as_uint(f);
  u += 0x7FFFu + ((u >> 16) & 1u);   // RNE
  return (unsigned short)(u >> 16);
}

__device__ __forceinline__ void async16(const void* g, void* l) {
  __builtin_amdgcn_global_load_lds(
      (const __attribute__((address_space(1))) void*)g,
      (__attribute__((address_space(3))) void*)l, 16, 0, 0);
}

// ---------------- fused prep: x casts + both weight transposes ----------------
__global__ __launch_bounds__(256) void prep_all_kernel(
    const float* __restrict__ x, const float* __restrict__ pos,
    const float* __restrict__ Wqkv, const float* __restrict__ Wout,
    unsigned short* __restrict__ X, unsigned short* __restrict__ XP,
    unsigned short* __restrict__ WQT, unsigned short* __restrict__ WOT) {
  __shared__ float tile[32][33];
  const int id = blockIdx.x;
  if (id < 4096) {
    const int i = (id * 256 + threadIdx.x) * 4;
    float4 xv = *(const float4*)(x + i);
    float4 pv = *(const float4*)(pos + (i & (SEQ * HDIM - 1)));
    ushort4 a, b;
    a.x = f2bf(xv.x); a.y = f2bf(xv.y); a.z = f2bf(xv.z); a.w = f2bf(xv.w);
    b.x = f2bf(xv.x + pv.x); b.y = f2bf(xv.y + pv.y);
    b.z = f2bf(xv.z + pv.z); b.w = f2bf(xv.w + pv.w);
    *(ushort4*)(X + i) = a;
    *(ushort4*)(XP + i) = b;
    return;
  }
  const float* in; unsigned short* out; int R, C, bx, by;
  if (id < 7168) {
    const int t2 = id - 4096;
    in = Wqkv; out = WQT; R = HDIM; C = 3 * HDIM;
    bx = (t2 % 96) * 32; by = (t2 / 96) * 32;
  } else {
    const int t3 = id - 7168;
    in = Wout; out = WOT; R = HDIM; C = HDIM;
    bx = (t3 & 31) * 32; by = (t3 >> 5) * 32;
  }
  const int tx = threadIdx.x & 31, ty = threadIdx.x >> 5;  // (32,8)
#pragma unroll
  for (int j = 0; j < 32; j += 8)
    tile[ty + j][tx] = in[(size_t)(by + ty + j) * C + bx + tx];
  __syncthreads();
#pragma unroll
  for (int j = 0; j < 32; j += 8)
    out[(size_t)(bx + ty + j) * R + by + tx] = f2bf(tile[tx][ty + j]);
}

// ---------------- GEMM1: C(4096x3072) = Aeff(4096x1024) @ Wt(3072x1024)^T ----------------
// R0 serial 2-barrier structure + R6 chunk-XOR LDS swizzle (CONFIRMED:
// SQ_LDS_BANK_CONFLICT 3.15M -> 0, 42.3us = 609 TF, at the 2-barrier-128^2
// structure ceiling; R1/R2/R3 measured all pipeline corners as regressions).
// Physical 16B-chunk p holds semantic chunk s = p ^ ((p>>3)&7); staging
// pre-permutes the GLOBAL source (m173 pattern); ds_reads apply the same XOR.
// V blocks compute C^T via operand swap so the V^T store is 32B s-runs.
__global__ __launch_bounds__(256) void gemm_qkv_kernel(
    const unsigned short* __restrict__ XP, const unsigned short* __restrict__ X,
    const unsigned short* __restrict__ Wt,
    unsigned short* __restrict__ Qb, unsigned short* __restrict__ Kb,
    unsigned short* __restrict__ VTb) {
  __shared__ unsigned short As[2][128 * 32];
  __shared__ unsigned short Bs[2][128 * 32];
  const int m0 = blockIdx.x * 128;
  const int n0 = blockIdx.y * 128;
  const bool isV = (n0 >= 2 * HDIM);
  const unsigned short* A = isV ? X : XP;
  const int t = threadIdx.x;
  const int lane = t & 63, w = t >> 6;
  const int wm = (w >> 1) * 64, wn = (w & 1) * 64;
  const int quad = lane >> 4, l15 = lane & 15;

  v4f acc[4][4] = {};

  const int s0c = t ^ ((t >> 3) & 7);
  const int rowA = s0c >> 2;          // 0..63
  const int colA = (s0c & 3) * 8;
  const unsigned short* gA = A + (size_t)(m0 + rowA) * HDIM + colA;
  const unsigned short* gB = Wt + (size_t)(n0 + rowA) * HDIM + colA;

  const int baseA = 4 * (wm + l15) + quad;
  const int pA0 = (baseA ^ ((baseA >> 3) & 7)) * 8;   // element offset, +i*512
  const int baseB = 4 * (wn + l15) + quad;
  const int pB0 = (baseB ^ ((baseB >> 3) & 7)) * 8;

  for (int k0 = 0; k0 < HDIM; k0 += 64) {
    __syncthreads();
#pragma unroll
    for (int kh = 0; kh < 2; kh++) {
      async16(gA + k0 + kh * 32, &As[kh][t * 8]);
      async16(gA + 64 * HDIM + k0 + kh * 32, &As[kh][2048 + t * 8]);
      async16(gB + k0 + kh * 32, &Bs[kh][t * 8]);
      async16(gB + 64 * HDIM + k0 + kh * 32, &Bs[kh][2048 + t * 8]);
    }
    __syncthreads();
#pragma unroll
    for (int kh = 0; kh < 2; kh++) {
      v8bf a[4], b[4];
#pragma unroll
      for (int i = 0; i < 4; i++)
        a[i] = *(const v8bf*)&As[kh][pA0 + i * 512];
#pragma unroll
      for (int i = 0; i < 4; i++)
        b[i] = *(const v8bf*)&Bs[kh][pB0 + i * 512];
      if (isV) {
#pragma unroll
        for (int i = 0; i < 4; i++)
#pragma unroll
          for (int j = 0; j < 4; j++)
            acc[i][j] = MFMA16(b[j], a[i], acc[i][j]);   // C^T
      } else {
#pragma unroll
        for (int i = 0; i < 4; i++)
#pragma unroll
          for (int j = 0; j < 4; j++)
            acc[i][j] = MFMA16(a[i], b[j], acc[i][j]);
      }
    }
  }

  const int b_ = m0 >> 11;
  const int s0 = m0 & (SEQ - 1);

  if (isV) {
    // acc[i][j] = C^T: D[row=quad*4+r -> Wt col (d)][col=l15 -> token (s)]
#pragma unroll
    for (int i = 0; i < 4; i++) {
#pragma unroll
      for (int j = 0; j < 4; j++) {
        const int s_ = s0 + wm + i * 16 + l15;
#pragma unroll
        for (int r = 0; r < 4; r++) {
          const int c2 = (n0 - 2 * HDIM) + wn + j * 16 + quad * 4 + r;
          const int h = c2 >> 6, d = c2 & 63;
          VTb[((size_t)(((b_ << 4) | h) * HS + d)) * SEQ + s_] = f2bf(acc[i][j][r]);
        }
      }
    }
  } else {
    // Q/K[(b,h,s), d]: scatter, 16 consecutive lanes form 32B d-runs
    const float scale = (n0 < HDIM) ? QSCALE : 1.0f;
    unsigned short* dst = (n0 < HDIM) ? Qb : Kb;
#pragma unroll
    for (int i = 0; i < 4; i++) {
#pragma unroll
      for (int j = 0; j < 4; j++) {
#pragma unroll
        for (int r = 0; r < 4; r++) {
          const int s_ = s0 + wm + i * 16 + quad * 4 + r;
          const int c2 = (n0 & (HDIM - 1)) + wn + j * 16 + l15;
          const int h = c2 >> 6, d = c2 & 63;
          dst[((size_t)(((b_ << 4) | h) * SEQ + s_)) * HS + d] =
              f2bf(acc[i][j][r] * scale);
        }
      }
    }
  }
}

// ---------------- flash attention, single-tile + async16 dbuf staging (R13) ----
// ONE 64-row q-tile per block, grid 32bh x 32q = 1024 blocks; heavy-first
// q = 31 - blockIdx.y; T5 setprio (R9). R13: staging converted from
// global->reg->LDS (4 uint4 loads + 4 ds_write_b128 + 2 barriers/chunk) to
// gemm_qkv's PROVEN async16 path: pre-permuted global source (R6 involution:
// phys chunk p of a [64][64] tile holds row p>>3, colchunk (p&7)^((p>>3)&7)),
// linear LDS dest, K/V double-buffered -> ONE barrier/chunk (its implicit
// vmcnt(0) drains the prefetch issued at top of the same iteration; chunk
// compute (18 MFMA + softmax) >> L2 latency so the drain is covered).
// WAR: dbuf + collective end barrier. Q/Ps region also linear [64][64] with
// the same XOR: bq/Ps reads use xq0/xq1 (row&7 = l15&7 since w*16==0 mod 8);
// Ps uint2 writes land at phys chunk (ni*2+quad>>1)^(l15&7), sub (quad&1)*4
// (hand-verified round-trip). LDS 40,960B -> exactly 4 blocks/CU.
__global__ __launch_bounds__(256, 2) void attn_pair_kernel(
    const unsigned short* __restrict__ Qp, const unsigned short* __restrict__ Kp,
    const unsigned short* __restrict__ Vp, unsigned short* __restrict__ ATTN) {
  __shared__ unsigned short SM[20480];       // 40,960 B
  unsigned short* Ks = SM;                   // [2][64][64] dbuf, XOR-swizzled
  unsigned short* Vs = SM + 8192;            // [2][64][64] dbuf (V^T: [d][key])
  unsigned short* QPs = SM + 16384;          // [64][64] union: Qs (init) / Ps

  const int bh = blockIdx.x;                 // 0..31
  const int qt = 31 - blockIdx.y;            // heavy-first
  const int b_ = bh >> 4, h = bh & 15;
  const int q0 = qt * 64;
  const int t = threadIdx.x;
  const int lane = t & 63, w = t >> 6;
  const int quad = lane >> 4, l15 = lane & 15;

  const unsigned short* Qg = Qp + (size_t)bh * SEQ * HS;
  const unsigned short* Kg = Kp + (size_t)bh * SEQ * HS;
  const unsigned short* Vg = Vp + (size_t)bh * HS * SEQ;

  // staging geometry: thread t owns physical chunks t and t+256
  const int rs = t >> 3;                      // tile row 0..31 (and +32)
  const int c8 = ((t & 7) ^ (rs & 7)) * 8;    // pre-permuted source col
  // fragment-read XORs (R7-verified)
  const int xq0 = (quad ^ (l15 & 7)) * 8;
  const int xq1 = ((quad + 4) ^ (l15 & 7)) * 8;
  // Ps write constants
  const int pxor = l15 & 7, q_hi = quad >> 1, q_lo = (quad & 1) * 4;

  // prologue: Q tile + K/V chunk 0, all via async16
  async16(Qg + (size_t)(q0 + rs) * HS + c8, &QPs[t * 8]);
  async16(Qg + (size_t)(q0 + rs + 32) * HS + c8, &QPs[t * 8 + 2048]);
  async16(Kg + (size_t)rs * HS + c8, &Ks[t * 8]);
  async16(Kg + (size_t)(rs + 32) * HS + c8, &Ks[t * 8 + 2048]);
  async16(Vg + (size_t)rs * SEQ + c8, &Vs[t * 8]);
  async16(Vg + (size_t)(rs + 32) * SEQ + c8, &Vs[t * 8 + 2048]);
  __syncthreads();   // drains all async16 (vmcnt 0) + makes Q visible

  // Q fragments: wave w reads ONLY its own rows w*16..w*16+15 (= its Ps region)
  v8bf bq[2];
#pragma unroll
  for (int kh = 0; kh < 2; kh++)
    bq[kh] = *(const v8bf*)&QPs[(w * 16 + l15) * 64 + (kh ? xq1 : xq0)];

  unsigned short* Ps_w = QPs + w * 1024;     // 16 rows/wave, [16][64] XOR'd

  v8bf ones;
#pragma unroll
  for (int j = 0; j < 8; j++) ones[j] = (__bf16)1.0f;

  v4f o[4] = {};
  v4f lacc = {};

  const int qrow = q0 + w * 16 + l15;  // lane's q-row in S^T

  for (int cI = 0; cI <= qt; cI++) {
    const int kc = cI * 64;
    const unsigned short* Kbuf = Ks + (cI & 1) * 4096;
    const unsigned short* Vbuf = Vs + (cI & 1) * 4096;
    if (cI < qt) {  // issue next chunk into the other buffers
      const int kn = kc + 64;
      unsigned short* Kn = Ks + ((cI + 1) & 1) * 4096;
      unsigned short* Vn = Vs + ((cI + 1) & 1) * 4096;
      async16(Kg + (size_t)(kn + rs) * HS + c8, &Kn[t * 8]);
      async16(Kg + (size_t)(kn + rs + 32) * HS + c8, &Kn[t * 8 + 2048]);
      async16(Vg + (size_t)rs * SEQ + kn + c8, &Vn[t * 8]);
      async16(Vg + (size_t)(rs + 32) * SEQ + kn + c8, &Vn[t * 8 + 2048]);
    }

    // K fragments (A-operand)
    v8bf kf0[4], kf1[4];
#pragma unroll
    for (int ni = 0; ni < 4; ni++) {
      kf0[ni] = *(const v8bf*)&Kbuf[(ni * 16 + l15) * 64 + xq0];
      kf1[ni] = *(const v8bf*)&Kbuf[(ni * 16 + l15) * 64 + xq1];
    }

    // ---- S^T = K Q^T, D[key=quad*4+r][qrow=l15] ----
    {
      v4f sc[4] = {};
      __builtin_amdgcn_s_setprio(1);
#pragma unroll
      for (int ni = 0; ni < 4; ni++) {
        sc[ni] = MFMA16(kf0[ni], bq[0], sc[ni]);
        sc[ni] = MFMA16(kf1[ni], bq[1], sc[ni]);
      }
      __builtin_amdgcn_s_setprio(0);
      if (cI == qt) {
#pragma unroll
        for (int ni = 0; ni < 4; ni++) {
          const int key = kc + ni * 16 + quad * 4;
#pragma unroll
          for (int r = 0; r < 4; r++)
            if (key + r > qrow) sc[ni][r] = -1e30f;
        }
      }
#pragma unroll
      for (int ni = 0; ni < 4; ni++) {
        const float p0 = exp2f(sc[ni][0]), p1 = exp2f(sc[ni][1]);
        const float p2 = exp2f(sc[ni][2]), p3 = exp2f(sc[ni][3]);
        uint2 pk;
        pk.x = __builtin_amdgcn_perm(__float_as_uint(p1), __float_as_uint(p0), 0x07060302u);
        pk.y = __builtin_amdgcn_perm(__float_as_uint(p3), __float_as_uint(p2), 0x07060302u);
        *(uint2*)&Ps_w[l15 * 64 + ((ni * 2 + q_hi) ^ pxor) * 8 + q_lo] = pk;
      }
    }

    // ---- O += P @ V, l += P @ 1 ----
    __builtin_amdgcn_s_setprio(1);
#pragma unroll
    for (int ki = 0; ki < 2; ki++) {
      v8bf pa = *(const v8bf*)&Ps_w[l15 * 64 + (ki ? xq1 : xq0)];
      lacc = MFMA16(pa, ones, lacc);
      const int xqk = ki ? xq1 : xq0;
#pragma unroll
      for (int ni = 0; ni < 4; ni++) {
        v8bf vb = *(const v8bf*)&Vbuf[(ni * 16 + l15) * 64 + xqk];
        o[ni] = MFMA16(pa, vb, o[ni]);
      }
    }
    __builtin_amdgcn_s_setprio(0);

    __syncthreads();  // drains next-chunk async16; orders dbuf WAR
  }

  // epilogue: normalize and store (C-layout rows = quad*4+r)
  const int row_base = q0 + w * 16 + quad * 4;
  float invl[4];
#pragma unroll
  for (int r = 0; r < 4; r++) invl[r] = 1.0f / lacc[r];
#pragma unroll
  for (int ni = 0; ni < 4; ni++)
#pragma unroll
    for (int r = 0; r < 4; r++) {
      const int tr = b_ * SEQ + row_base + r;
      ATTN[(size_t)tr * HDIM + h * HS + ni * 16 + l15] = f2bf(o[ni][r] * invl[r]);
    }
}

// ---------------- GEMM2: out(4096x1024) = ATTN @ WOT^T, fp32 out ----------------
// 64x64-tile clone of gemm_qkv's serial BK=64 2-barrier structure (R10).
// Chunk-XOR swizzle carried over verbatim (R6-verified).
__global__ __launch_bounds__(256) void gemm_out_kernel(
    const unsigned short* __restrict__ Ab, const unsigned short* __restrict__ Wt,
    float* __restrict__ out) {
  __shared__ unsigned short As[2][64 * 32];
  __shared__ unsigned short Bs[2][64 * 32];
  const int m0 = blockIdx.x * 64;
  const int n0 = blockIdx.y * 64;
  const int t = threadIdx.x;
  const int lane = t & 63, w = t >> 6;
  const int wm = (w >> 1) * 32, wn = (w & 1) * 32;   // wave tile 32x32
  const int quad = lane >> 4, l15 = lane & 15;

  v4f acc[2][2] = {};

  const int s0c = t ^ ((t >> 3) & 7);
  const int rowA = s0c >> 2;          // 0..63
  const int colA = (s0c & 3) * 8;
  const unsigned short* gA = Ab + (size_t)(m0 + rowA) * HDIM + colA;
  const unsigned short* gB = Wt + (size_t)(n0 + rowA) * HDIM + colA;

  const int baseA = 4 * (wm + l15) + quad;
  const int pA0 = (baseA ^ ((baseA >> 3) & 7)) * 8;
  const int baseB = 4 * (wn + l15) + quad;
  const int pB0 = (baseB ^ ((baseB >> 3) & 7)) * 8;

  for (int k0 = 0; k0 < HDIM; k0 += 64) {
    __syncthreads();
#pragma unroll
    for (int kh = 0; kh < 2; kh++) {
      async16(gA + k0 + kh * 32, &As[kh][t * 8]);
      async16(gB + k0 + kh * 32, &Bs[kh][t * 8]);
    }
    __syncthreads();
#pragma unroll
    for (int kh = 0; kh < 2; kh++) {
      v8bf a[2], b[2];
#pragma unroll
      for (int i = 0; i < 2; i++)
        a[i] = *(const v8bf*)&As[kh][pA0 + i * 512];
#pragma unroll
      for (int j = 0; j < 2; j++)
        b[j] = *(const v8bf*)&Bs[kh][pB0 + j * 512];
#pragma unroll
      for (int i = 0; i < 2; i++)
#pragma unroll
        for (int j = 0; j < 2; j++)
          acc[i][j] = MFMA16(a[i], b[j], acc[i][j]);
    }
  }

#pragma unroll
  for (int i = 0; i < 2; i++) {
#pragma unroll
    for (int j = 0; j < 2; j++) {
#pragma unroll
      for (int r = 0; r < 4; r++) {
        const int tr = m0 + wm + i * 16 + quad * 4 + r;
        const int c = n0 + wn + j * 16 + l15;
        out[(size_t)tr * HDIM + c] = acc[i][j][r];
      }
    }
  }
}

extern "C" void kernel_launch(void* const* d_in, const int* in_sizes, int n_in,
                              void* d_out, int out_size, void* d_ws, size_t ws_size,
                              hipStream_t stream) {
  (void)in_sizes; (void)n_in; (void)out_size; (void)ws_size;
  const float* x    = (const float*)d_in[0];
  const float* pos  = (const float*)d_in[1];
  const float* Wqkv = (const float*)d_in[2];
  const float* Wout = (const float*)d_in[3];
  float* out = (float*)d_out;

  char* ws = (char*)d_ws;
  unsigned short* XP   = (unsigned short*)(ws);
  unsigned short* X    = (unsigned short*)(ws + ((size_t)8  << 20));
  unsigned short* WQT  = (unsigned short*)(ws + ((size_t)16 << 20));
  unsigned short* WOT  = (unsigned short*)(ws + ((size_t)22 << 20));
  unsigned short* Qb   = (unsigned short*)(ws + ((size_t)24 << 20));
  unsigned short* Kb   = (unsigned short*)(ws + ((size_t)32 << 20));
  unsigned short* VTb  = (unsigned short*)(ws + ((size_t)40 << 20));
  unsigned short* ATTN = (unsigned short*)(ws + ((size_t)48 << 20));

  prep_all_kernel<<<8192, 256, 0, stream>>>(x, pos, Wqkv, Wout, X, XP, WQT, WOT);

  dim3 g1(TOKENS / 128, 3 * HDIM / 128);
  gemm_qkv_kernel<<<g1, 256, 0, stream>>>(XP, X, WQT, Qb, Kb, VTb);

  dim3 g2(2 * NHEADS, 32);
  attn_pair_kernel<<<g2, 256, 0, stream>>>(Qb, Kb, VTb, ATTN);

  dim3 g3(TOKENS / 64, HDIM / 64);
  gemm_out_kernel<<<g3, 256, 0, stream>>>(ATTN, WOT, out);
}